// Round 8
// baseline (541.826 us; speedup 1.0000x reference)
//
#include <hip/hip_runtime.h>

typedef _Float16 half8 __attribute__((ext_vector_type(8)));
typedef _Float16 half4v __attribute__((ext_vector_type(4)));
typedef float f32x4 __attribute__((ext_vector_type(4)));

#define OFF_PRED 26214400      // 32*128*128*50
#define OFF_XU   56934400      // OFF_PRED + 32*64*300*50
#define NBP 8                  // bp per block; grid = 2048/NBP = 256 = 1 block/CU

// ---- K0: build M in MFMA-fragment order.
// Logical M[640][320]: rows 0..255 = C, 256..555 = A, rest 0; cols k<300 real, else 0.
// dst elem = ((mt*10 + ks)*64 + lane)*8 + e, m = mt*16 + (lane&15), k = ks*32 + (lane>>4)*8 + e.
__global__ void build_M(const float* __restrict__ A, const float* __restrict__ C,
                        _Float16* __restrict__ M) {
    int idx = blockIdx.x * 256 + threadIdx.x;
    if (idx >= 640 * 320) return;
    int e    = idx & 7;
    int lane = (idx >> 3) & 63;
    int fs   = idx >> 9;                        // mt*10 + ks
    int mt = fs / 10, ks = fs % 10;
    int m = mt * 16 + (lane & 15);
    int k = ks * 32 + (lane >> 4) * 8 + e;
    float v = 0.f;
    if (k < 300) {
        if (m < 256) v = C[m * 300 + k];
        else if (m < 556) v = A[(m - 256) * 300 + k];
    }
    M[idx] = (_Float16)v;
}

// ---- K1: persistent block, NBP bp's, double-buffered LDS, 2-phase pipeline.
//      16 waves: wave w -> g=w>>1 (m-rows 80g..80g+80), h=w&1 (n-cols 32h..32h+32).
//      LDS buffer: 64 rows x 320 fp16, stride 640 B, swz: byte ^ ((row&7)<<4).
__global__ __launch_bounds__(1024, 1) void gemm_main(
    const float* __restrict__ X, const float* __restrict__ x0,
    const _Float16* __restrict__ M, float* __restrict__ out)
{
    extern __shared__ char ldsraw[];            // 2 x 40960 B
    const int tid = threadIdx.x;
    const int wave = tid >> 6, lane = tid & 63;
    const int lr = lane & 15, lg = lane >> 4;
    const int g = wave >> 1, h = wave & 1;
    const int bp0 = blockIdx.x * NBP;

    // per-thread staging coordinates: item i = tid + u*1024 -> (t = i%50, j = i/50)
    int st_t[4], st_j[4];
    #pragma unroll
    for (int u = 0; u < 4; u++) { int i = tid + u * 1024; st_t[u] = i % 50; st_j[u] = i / 50; }
    const bool v3 = tid < 678;                  // item u=3 valid (3750-3072)

    // B-frag base (fragment-ordered M): frag (mt=g*5+j, ks) = contiguous 1KB at ((mt*10+ks)*512)
    const _Float16* Mw = M + g * 50 * 512 + lane * 8;

    // zero-fill both buffers (pad cols & rows 51..63 stay zero forever)
    #pragma unroll
    for (int u = 0; u < 10; u++)
        *(unsigned long long*)(ldsraw + tid * 8 + u * 8192) = 0ULL;
    __syncthreads();

    float sx[4][4];
    float s0x[4];

    // ---- stage_load(bp0) ----
    {
        const float* Xb = X + bp0 * 15000;
        #pragma unroll
        for (int u = 0; u < 4; u++) if (u < 3 || v3) {
            const float* s = Xb + st_j[u] * 200 + st_t[u];
            sx[u][0] = s[0]; sx[u][1] = s[50]; sx[u][2] = s[100]; sx[u][3] = s[150];
        }
        if (tid < 75) {
            f32x4 v = *(const f32x4*)(x0 + bp0 * 300 + tid * 4);
            s0x[0] = v.x; s0x[1] = v.y; s0x[2] = v.z; s0x[3] = v.w;
        }
    }
    // ---- stage_write(buf0) ----
    {
        char* wb = ldsraw;
        #pragma unroll
        for (int u = 0; u < 4; u++) if (u < 3 || v3) {
            int row = st_t[u] + 1;
            half4v h4 = {(_Float16)sx[u][0], (_Float16)sx[u][1], (_Float16)sx[u][2], (_Float16)sx[u][3]};
            *(half4v*)(wb + row * 640 + ((st_j[u] * 8) ^ ((row & 7) << 4))) = h4;
        }
        if (tid < 75) {
            half4v h4 = {(_Float16)s0x[0], (_Float16)s0x[1], (_Float16)s0x[2], (_Float16)s0x[3]};
            *(half4v*)(wb + tid * 8) = h4;      // row 0, swizzle identity
        }
    }
    __syncthreads();

    // A-frag: local row = h*32 + nt*16 + lr
    #define LDSA(base, nt, ks) (*(const half8*)((base) + (h * 32 + (nt) * 16 + lr) * 640 + \
                               (((ks) * 64 + lg * 16) ^ ((lr & 7) << 4))))

    for (int it = 0; it < NBP; ++it) {
        const int bp = bp0 + it;
        const int b = bp >> 6, p = bp & 63;
        char* ldsb = ldsraw + (it & 1) * 40960;

        // ---- issue next bp's global loads (latency hides under compute) ----
        if (it + 1 < NBP) {
            const float* Xb = X + (bp + 1) * 15000;
            #pragma unroll
            for (int u = 0; u < 4; u++) if (u < 3 || v3) {
                const float* s = Xb + st_j[u] * 200 + st_t[u];
                sx[u][0] = s[0]; sx[u][1] = s[50]; sx[u][2] = s[100]; sx[u][3] = s[150];
            }
            if (tid < 75) {
                f32x4 v = *(const f32x4*)(x0 + (bp + 1) * 300 + tid * 4);
                s0x[0] = v.x; s0x[1] = v.y; s0x[2] = v.z; s0x[3] = v.w;
            }
        }

        // ---- compute ----
        f32x4 acc[5][2];
        #pragma unroll
        for (int j = 0; j < 5; j++)
            #pragma unroll
            for (int nt = 0; nt < 2; nt++)
                acc[j][nt] = (f32x4){0.f, 0.f, 0.f, 0.f};

        #pragma unroll
        for (int ks = 0; ks < 10; ks++) {
            half8 bf0 = *(const half8*)(Mw + (0 * 10 + ks) * 512);
            half8 bf1 = *(const half8*)(Mw + (1 * 10 + ks) * 512);
            half8 bf2 = *(const half8*)(Mw + (2 * 10 + ks) * 512);
            half8 bf3 = *(const half8*)(Mw + (3 * 10 + ks) * 512);
            half8 bf4 = *(const half8*)(Mw + (4 * 10 + ks) * 512);
            #pragma unroll
            for (int nt = 0; nt < 2; nt++) {
                half8 a = LDSA(ldsb, nt, ks);
                acc[0][nt] = __builtin_amdgcn_mfma_f32_16x16x32_f16(a, bf0, acc[0][nt], 0, 0, 0);
                acc[1][nt] = __builtin_amdgcn_mfma_f32_16x16x32_f16(a, bf1, acc[1][nt], 0, 0, 0);
                acc[2][nt] = __builtin_amdgcn_mfma_f32_16x16x32_f16(a, bf2, acc[2][nt], 0, 0, 0);
                acc[3][nt] = __builtin_amdgcn_mfma_f32_16x16x32_f16(a, bf3, acc[3][nt], 0, 0, 0);
                acc[4][nt] = __builtin_amdgcn_mfma_f32_16x16x32_f16(a, bf4, acc[4][nt], 0, 0, 0);
            }
        }

        // ---- epilogue: col m = g*80 + j*16 + lr, ext-col n = h*32 + nt*16 + lg*4 + q ----
        {
            const int gr = p >> 3, gc = p & 7;
            #pragma unroll
            for (int j = 0; j < 5; j++) {
                int colm = g * 80 + j * 16 + lr;
                if (colm < 256) {
                    int base = b * 819200 + ((gr * 16 + (colm >> 4)) * 128 + gc * 16 + (colm & 15)) * 50;
                    #pragma unroll
                    for (int nt = 0; nt < 2; nt++) {
                        int t0 = h * 32 + nt * 16 + lg * 4;
                        if (t0 == 0) {
                            out[base + 0] = acc[j][0][1];
                            out[base + 1] = acc[j][0][2];
                            out[base + 2] = acc[j][0][3];
                        } else if (t0 <= 46) {
                            f32x4 v = acc[j][nt];
                            __builtin_memcpy(&out[base + t0 - 1], &v, 16);
                        } else if (t0 == 48) {
                            out[base + 47] = acc[j][nt][0];
                            out[base + 48] = acc[j][nt][1];
                            out[base + 49] = acc[j][nt][2];
                        }
                    }
                } else if (colm < 556) {
                    int base = OFF_PRED + (bp * 300 + (colm - 256)) * 50;
                    #pragma unroll
                    for (int nt = 0; nt < 2; nt++) {
                        int t0 = h * 32 + nt * 16 + lg * 4;
                        if (t0 <= 46) {
                            f32x4 v = acc[j][nt];
                            __builtin_memcpy(&out[base + t0], &v, 16);
                        } else if (t0 == 48) {
                            out[base + 48] = acc[j][nt][0];
                            out[base + 49] = acc[j][nt][1];
                        }
                    }
                }
            }
        }

        // ---- write next bp's tile into the other buffer ----
        if (it + 1 < NBP) {
            char* wb = ldsraw + ((it & 1) ^ 1) * 40960;
            #pragma unroll
            for (int u = 0; u < 4; u++) if (u < 3 || v3) {
                int row = st_t[u] + 1;
                half4v h4 = {(_Float16)sx[u][0], (_Float16)sx[u][1], (_Float16)sx[u][2], (_Float16)sx[u][3]};
                *(half4v*)(wb + row * 640 + ((st_j[u] * 8) ^ ((row & 7) << 4))) = h4;
            }
            if (tid < 75) {
                half4v h4 = {(_Float16)s0x[0], (_Float16)s0x[1], (_Float16)s0x[2], (_Float16)s0x[3]};
                *(half4v*)(wb + tid * 8) = h4;
            }
        }
        __syncthreads();
    }
    #undef LDSA
}

// ---- K2: X_U[b,i,t] = 0.5*(1+exp(-(B·U)[b,i,t])) * sum_p |X[b,p,i,t]|
__global__ void xu_kernel(const float* __restrict__ X, const float* __restrict__ U,
                          const float* __restrict__ B, float* __restrict__ out) {
    int id = blockIdx.x * 256 + threadIdx.x;
    if (id >= 480000) return;
    int t = id % 50;
    int i = (id / 50) % 300;
    int b = id / 15000;
    const float* xp = X + b * 960000 + i * 50 + t;
    float s = 0.f;
    #pragma unroll 8
    for (int pp = 0; pp < 64; pp++) s += fabsf(xp[pp * 15000]);
    float bu = 0.f;
    const float* up = U + b * 2000 + t;
    const float* Bp = B + i * 40;
    #pragma unroll 8
    for (int q = 0; q < 40; q++) bu += Bp[q] * up[q * 50];
    out[OFF_XU + id] = 0.5f * (1.f + expf(-bu)) * s;
}

extern "C" void kernel_launch(void* const* d_in, const int* in_sizes, int n_in,
                              void* d_out, int out_size, void* d_ws, size_t ws_size,
                              hipStream_t stream) {
    const float* X  = (const float*)d_in[0];
    const float* U  = (const float*)d_in[1];
    const float* x0 = (const float*)d_in[2];
    const float* A  = (const float*)d_in[3];
    const float* B  = (const float*)d_in[4];
    const float* C  = (const float*)d_in[5];
    float* out = (float*)d_out;
    _Float16* M = (_Float16*)d_ws;      // 640*320*2 = 409,600 B (fragment-ordered)

    build_M<<<800, 256, 0, stream>>>(A, C, M);
    gemm_main<<<256, 1024, 81920, stream>>>(X, x0, M, out);
    xu_kernel<<<1875, 256, 0, stream>>>(X, U, B, out);
}

// Round 9
// 147.896 us; speedup vs baseline: 3.6636x; 3.6636x over previous
//
#include <hip/hip_runtime.h>

typedef _Float16 half8 __attribute__((ext_vector_type(8)));
typedef _Float16 half4v __attribute__((ext_vector_type(4)));
typedef float f32x4 __attribute__((ext_vector_type(4)));

#define OFF_PRED 26214400      // 32*128*128*50
#define OFF_XU   56934400      // OFF_PRED + 32*64*300*50

// ---- K0: build M in MFMA-fragment order.
// Logical M[640][320]: rows 0..255 = C, 256..555 = A, rest 0; cols k<300 real, else 0.
// dst elem = ((mt*10 + ks)*64 + lane)*8 + e, m = mt*16 + (lane&15), k = ks*32 + (lane>>4)*8 + e.
__global__ void build_M(const float* __restrict__ A, const float* __restrict__ C,
                        _Float16* __restrict__ M) {
    int idx = blockIdx.x * 256 + threadIdx.x;
    if (idx >= 640 * 320) return;
    int e    = idx & 7;
    int lane = (idx >> 3) & 63;
    int fs   = idx >> 9;                        // mt*10 + ks
    int mt = fs / 10, ks = fs % 10;
    int m = mt * 16 + (lane & 15);
    int k = ks * 32 + (lane >> 4) * 8 + e;
    float v = 0.f;
    if (k < 300) {
        if (m < 256) v = C[m * 300 + k];
        else if (m < 556) v = A[(m - 256) * 300 + k];
    }
    M[idx] = (_Float16)v;
}

// ---- K1: block (bp, mhalf): rows [320*mhalf, 320*mhalf+320) of Y = M · [x0 | X_bp].
//      512 thr / 8 waves: wave w -> local m-group g=w>>1 (80 rows), n-half h=w&1 (32 cols).
//      acc = 5x2 = 40. 2 blocks/CU co-resident -> stage/compute overlap across blocks.
//      LDS: 64 rows x 320 fp16, stride 640 B, swz: byte ^ ((row&7)<<4).
__global__ __launch_bounds__(512, 4) void gemm_main(
    const float* __restrict__ X, const float* __restrict__ x0,
    const _Float16* __restrict__ M, float* __restrict__ out)
{
    __shared__ _Float16 lds[64 * 320];   // 40960 B
    char* ldsb = (char*)lds;
    const int bid = blockIdx.x;
    const int bp = bid >> 1, mhalf = bid & 1;
    const int b = bp >> 6, p = bp & 63;
    const int tid = threadIdx.x;
    const float* Xbp = X + bp * 15000;

    const int wave = tid >> 6, lane = tid & 63;
    const int lr = lane & 15, lg = lane >> 4;
    const int g = wave >> 1, h = wave & 1;

    // zero-fill whole LDS (pad cols 300..319 and rows 51..63 stay zero)
    #pragma unroll
    for (int u = 0; u < 10; u++)
        *(unsigned long long*)(ldsb + tid * 8 + u * 4096) = 0ULL;
    __syncthreads();

    // x0 -> row 0 (row 0 swizzle = identity)
    if (tid < 75) {
        f32x4 v = *(const f32x4*)(x0 + bp * 300 + tid * 4);
        half4v h4 = { (_Float16)v.x, (_Float16)v.y, (_Float16)v.z, (_Float16)v.w };
        *(half4v*)(ldsb + tid * 8) = h4;
    }
    // X (k-major [300][50]) -> LDS rows n=t+1 (transposed), 8B swizzled writes
    for (int i = tid; i < 3750; i += 512) {
        int t = i % 50, jq = i / 50;
        const float* s = Xbp + (jq * 4) * 50 + t;
        half4v h4 = { (_Float16)s[0], (_Float16)s[50], (_Float16)s[100], (_Float16)s[150] };
        int row = t + 1;
        *(half4v*)(ldsb + row * 640 + ((jq * 8) ^ ((row & 7) << 4))) = h4;
    }
    __syncthreads();

    f32x4 acc[5][2];
    #pragma unroll
    for (int j = 0; j < 5; j++)
        #pragma unroll
        for (int nt = 0; nt < 2; nt++)
            acc[j][nt] = (f32x4){0.f, 0.f, 0.f, 0.f};

    // B-frag (fragment-ordered M): global m-group = mhalf*4 + g, 5 mt each, frag = 1KB
    const _Float16* Mw = M + (mhalf * 4 + g) * 50 * 512 + lane * 8;
    // A-frag: local row = h*32 + nt*16 + lr
    #define LDSA(nt, ks) (*(const half8*)(ldsb + (h * 32 + (nt) * 16 + lr) * 640 + \
                         (((ks) * 64 + lg * 16) ^ ((lr & 7) << 4))))

    #pragma unroll
    for (int ks = 0; ks < 10; ks++) {
        half8 bf0 = *(const half8*)(Mw + (0 * 10 + ks) * 512);
        half8 bf1 = *(const half8*)(Mw + (1 * 10 + ks) * 512);
        half8 bf2 = *(const half8*)(Mw + (2 * 10 + ks) * 512);
        half8 bf3 = *(const half8*)(Mw + (3 * 10 + ks) * 512);
        half8 bf4 = *(const half8*)(Mw + (4 * 10 + ks) * 512);
        #pragma unroll
        for (int nt = 0; nt < 2; nt++) {
            half8 a = LDSA(nt, ks);
            acc[0][nt] = __builtin_amdgcn_mfma_f32_16x16x32_f16(a, bf0, acc[0][nt], 0, 0, 0);
            acc[1][nt] = __builtin_amdgcn_mfma_f32_16x16x32_f16(a, bf1, acc[1][nt], 0, 0, 0);
            acc[2][nt] = __builtin_amdgcn_mfma_f32_16x16x32_f16(a, bf2, acc[2][nt], 0, 0, 0);
            acc[3][nt] = __builtin_amdgcn_mfma_f32_16x16x32_f16(a, bf3, acc[3][nt], 0, 0, 0);
            acc[4][nt] = __builtin_amdgcn_mfma_f32_16x16x32_f16(a, bf4, acc[4][nt], 0, 0, 0);
        }
    }

    // epilogue: col m = mhalf*320 + g*80 + j*16 + lr, ext-col n = h*32 + nt*16 + lg*4 + q
    const int gr = p >> 3, gc = p & 7;
    #pragma unroll
    for (int j = 0; j < 5; j++) {
        int colm = mhalf * 320 + g * 80 + j * 16 + lr;
        if (colm < 256) {
            // recon row d = colm -> vid[b][gr*16 + d/16][gc*16 + d%16][t], t = n-1
            int base = b * 819200 + ((gr * 16 + (colm >> 4)) * 128 + gc * 16 + (colm & 15)) * 50;
            #pragma unroll
            for (int nt = 0; nt < 2; nt++) {
                int t0 = h * 32 + nt * 16 + lg * 4;
                if (t0 == 0) {
                    out[base + 0] = acc[j][0][1];
                    out[base + 1] = acc[j][0][2];
                    out[base + 2] = acc[j][0][3];
                } else if (t0 <= 46) {
                    f32x4 v = acc[j][nt];
                    __builtin_memcpy(&out[base + t0 - 1], &v, 16);
                } else if (t0 == 48) {
                    out[base + 47] = acc[j][nt][0];
                    out[base + 48] = acc[j][nt][1];
                    out[base + 49] = acc[j][nt][2];
                }
            }
        } else if (colm < 556) {
            // X_pred row i = colm-256, t = n
            int base = OFF_PRED + (bp * 300 + (colm - 256)) * 50;
            #pragma unroll
            for (int nt = 0; nt < 2; nt++) {
                int t0 = h * 32 + nt * 16 + lg * 4;
                if (t0 <= 46) {
                    f32x4 v = acc[j][nt];
                    __builtin_memcpy(&out[base + t0], &v, 16);
                } else if (t0 == 48) {
                    out[base + 48] = acc[j][nt][0];
                    out[base + 49] = acc[j][nt][1];
                }
            }
        }
    }
}

// ---- K2: X_U[b,i,t] = 0.5*(1+exp(-(B·U)[b,i,t])) * sum_p |X[b,p,i,t]|
__global__ void xu_kernel(const float* __restrict__ X, const float* __restrict__ U,
                          const float* __restrict__ B, float* __restrict__ out) {
    int id = blockIdx.x * 256 + threadIdx.x;
    if (id >= 480000) return;
    int t = id % 50;
    int i = (id / 50) % 300;
    int b = id / 15000;
    const float* xp = X + b * 960000 + i * 50 + t;
    float s = 0.f;
    #pragma unroll 8
    for (int pp = 0; pp < 64; pp++) s += fabsf(xp[pp * 15000]);
    float bu = 0.f;
    const float* up = U + b * 2000 + t;
    const float* Bp = B + i * 40;
    #pragma unroll 8
    for (int q = 0; q < 40; q++) bu += Bp[q] * up[q * 50];
    out[OFF_XU + id] = 0.5f * (1.f + expf(-bu)) * s;
}

extern "C" void kernel_launch(void* const* d_in, const int* in_sizes, int n_in,
                              void* d_out, int out_size, void* d_ws, size_t ws_size,
                              hipStream_t stream) {
    const float* X  = (const float*)d_in[0];
    const float* U  = (const float*)d_in[1];
    const float* x0 = (const float*)d_in[2];
    const float* A  = (const float*)d_in[3];
    const float* B  = (const float*)d_in[4];
    const float* C  = (const float*)d_in[5];
    float* out = (float*)d_out;
    _Float16* M = (_Float16*)d_ws;      // 640*320*2 = 409,600 B (fragment-ordered)

    build_M<<<800, 256, 0, stream>>>(A, C, M);
    gemm_main<<<4096, 512, 0, stream>>>(X, x0, M, out);
    xu_kernel<<<1875, 256, 0, stream>>>(X, U, B, out);
}

// Round 10
// 144.528 us; speedup vs baseline: 3.7489x; 1.0233x over previous
//
#include <hip/hip_runtime.h>

typedef _Float16 half8 __attribute__((ext_vector_type(8)));
typedef _Float16 half4v __attribute__((ext_vector_type(4)));
typedef float f32x4 __attribute__((ext_vector_type(4)));

#define OFF_PRED 26214400      // 32*128*128*50
#define OFF_XU   56934400      // OFF_PRED + 32*64*300*50

// ---- K0: build M in MFMA-fragment order.
// Logical M[640][320]: rows 0..255 = C, 256..555 = A, rest 0; cols k<300 real, else 0.
// dst elem = ((mt*10 + ks)*64 + lane)*8 + e, m = mt*16 + (lane&15), k = ks*32 + (lane>>4)*8 + e.
__global__ void build_M(const float* __restrict__ A, const float* __restrict__ C,
                        _Float16* __restrict__ M) {
    int idx = blockIdx.x * 256 + threadIdx.x;
    if (idx >= 640 * 320) return;
    int e    = idx & 7;
    int lane = (idx >> 3) & 63;
    int fs   = idx >> 9;                        // mt*10 + ks
    int mt = fs / 10, ks = fs % 10;
    int m = mt * 16 + (lane & 15);
    int k = ks * 32 + (lane >> 4) * 8 + e;
    float v = 0.f;
    if (k < 300) {
        if (m < 256) v = C[m * 300 + k];
        else if (m < 556) v = A[(m - 256) * 300 + k];
    }
    M[idx] = (_Float16)v;
}

// ---- K1: block (bp, mhalf): rows [320*mhalf, 320*mhalf+320) of Y = M · [x0 | X_bp].
//      256 thr / 4 waves: wave g owns m-rows [80g,80g+80) of the half (5 mt) x ALL 4 n-tiles.
//      acc = 5x4 = 80 AGPR; B-frag reuse doubled vs nt=2 -> M L2 traffic halves.
//      reg cap 170 (launch_bounds(256,3)) -> 3 waves/SIMD -> 3 blocks/CU co-resident.
//      LDS: 64 rows x 320 fp16, stride 640 B, swz: byte ^ ((row&7)<<4).
__global__ __launch_bounds__(256, 3) void gemm_main(
    const float* __restrict__ X, const float* __restrict__ x0,
    const _Float16* __restrict__ M, float* __restrict__ out)
{
    __shared__ _Float16 lds[64 * 320];   // 40960 B
    char* ldsb = (char*)lds;
    const int bid = blockIdx.x;
    const int bp = bid >> 1, mhalf = bid & 1;
    const int b = bp >> 6, p = bp & 63;
    const int tid = threadIdx.x;
    const float* Xbp = X + bp * 15000;

    const int wave = tid >> 6, lane = tid & 63;
    const int lr = lane & 15, lg = lane >> 4;
    const int g = wave;

    // zero-fill whole LDS (pad cols 300..319 and rows 51..63 stay zero)
    #pragma unroll
    for (int u = 0; u < 20; u++)
        *(unsigned long long*)(ldsb + tid * 8 + u * 2048) = 0ULL;
    __syncthreads();

    // x0 -> row 0 (row 0 swizzle = identity)
    if (tid < 75) {
        f32x4 v = *(const f32x4*)(x0 + bp * 300 + tid * 4);
        half4v h4 = { (_Float16)v.x, (_Float16)v.y, (_Float16)v.z, (_Float16)v.w };
        *(half4v*)(ldsb + tid * 8) = h4;
    }
    // X (k-major [300][50]) -> LDS rows n=t+1 (transposed), 8B swizzled writes
    for (int i = tid; i < 3750; i += 256) {
        int t = i % 50, jq = i / 50;
        const float* s = Xbp + (jq * 4) * 50 + t;
        half4v h4 = { (_Float16)s[0], (_Float16)s[50], (_Float16)s[100], (_Float16)s[150] };
        int row = t + 1;
        *(half4v*)(ldsb + row * 640 + ((jq * 8) ^ ((row & 7) << 4))) = h4;
    }
    __syncthreads();

    f32x4 acc[5][4];
    #pragma unroll
    for (int j = 0; j < 5; j++)
        #pragma unroll
        for (int nt = 0; nt < 4; nt++)
            acc[j][nt] = (f32x4){0.f, 0.f, 0.f, 0.f};

    // B-frag (fragment-ordered M): global m-group = mhalf*4 + g, frag (mt,ks) = 1KB burst
    const _Float16* Mw = M + (mhalf * 4 + g) * 50 * 512 + lane * 8;
    // A-frag: row = nt*16 + lr
    #define LDSA(nt, ks) (*(const half8*)(ldsb + ((nt) * 16 + lr) * 640 + \
                         (((ks) * 64 + lg * 16) ^ ((lr & 7) << 4))))

    #pragma unroll
    for (int ks = 0; ks < 10; ks++) {
        half8 bf0 = *(const half8*)(Mw + (0 * 10 + ks) * 512);
        half8 bf1 = *(const half8*)(Mw + (1 * 10 + ks) * 512);
        half8 bf2 = *(const half8*)(Mw + (2 * 10 + ks) * 512);
        half8 bf3 = *(const half8*)(Mw + (3 * 10 + ks) * 512);
        half8 bf4 = *(const half8*)(Mw + (4 * 10 + ks) * 512);
        #pragma unroll
        for (int nt = 0; nt < 4; nt++) {
            half8 a = LDSA(nt, ks);
            acc[0][nt] = __builtin_amdgcn_mfma_f32_16x16x32_f16(a, bf0, acc[0][nt], 0, 0, 0);
            acc[1][nt] = __builtin_amdgcn_mfma_f32_16x16x32_f16(a, bf1, acc[1][nt], 0, 0, 0);
            acc[2][nt] = __builtin_amdgcn_mfma_f32_16x16x32_f16(a, bf2, acc[2][nt], 0, 0, 0);
            acc[3][nt] = __builtin_amdgcn_mfma_f32_16x16x32_f16(a, bf3, acc[3][nt], 0, 0, 0);
            acc[4][nt] = __builtin_amdgcn_mfma_f32_16x16x32_f16(a, bf4, acc[4][nt], 0, 0, 0);
        }
    }

    // epilogue: col m = mhalf*320 + g*80 + j*16 + lr, ext-col n = nt*16 + lg*4 + q
    const int gr = p >> 3, gc = p & 7;
    #pragma unroll
    for (int j = 0; j < 5; j++) {
        int colm = mhalf * 320 + g * 80 + j * 16 + lr;
        if (colm < 256) {
            // recon row d = colm -> vid[b][gr*16 + d/16][gc*16 + d%16][t], t = n-1
            int base = b * 819200 + ((gr * 16 + (colm >> 4)) * 128 + gc * 16 + (colm & 15)) * 50;
            #pragma unroll
            for (int nt = 0; nt < 4; nt++) {
                int t0 = nt * 16 + lg * 4;
                if (t0 == 0) {
                    out[base + 0] = acc[j][0][1];
                    out[base + 1] = acc[j][0][2];
                    out[base + 2] = acc[j][0][3];
                } else if (t0 <= 46) {
                    f32x4 v = acc[j][nt];
                    __builtin_memcpy(&out[base + t0 - 1], &v, 16);
                } else if (t0 == 48) {
                    out[base + 47] = acc[j][nt][0];
                    out[base + 48] = acc[j][nt][1];
                    out[base + 49] = acc[j][nt][2];
                }
            }
        } else if (colm < 556) {
            // X_pred row i = colm-256, t = n
            int base = OFF_PRED + (bp * 300 + (colm - 256)) * 50;
            #pragma unroll
            for (int nt = 0; nt < 4; nt++) {
                int t0 = nt * 16 + lg * 4;
                if (t0 <= 46) {
                    f32x4 v = acc[j][nt];
                    __builtin_memcpy(&out[base + t0], &v, 16);
                } else if (t0 == 48) {
                    out[base + 48] = acc[j][nt][0];
                    out[base + 49] = acc[j][nt][1];
                }
            }
        }
    }
}

// ---- K2: X_U[b,i,t] = 0.5*(1+exp(-(B·U)[b,i,t])) * sum_p |X[b,p,i,t]|
__global__ void xu_kernel(const float* __restrict__ X, const float* __restrict__ U,
                          const float* __restrict__ B, float* __restrict__ out) {
    int id = blockIdx.x * 256 + threadIdx.x;
    if (id >= 480000) return;
    int t = id % 50;
    int i = (id / 50) % 300;
    int b = id / 15000;
    const float* xp = X + b * 960000 + i * 50 + t;
    float s = 0.f;
    #pragma unroll 8
    for (int pp = 0; pp < 64; pp++) s += fabsf(xp[pp * 15000]);
    float bu = 0.f;
    const float* up = U + b * 2000 + t;
    const float* Bp = B + i * 40;
    #pragma unroll 8
    for (int q = 0; q < 40; q++) bu += Bp[q] * up[q * 50];
    out[OFF_XU + id] = 0.5f * (1.f + expf(-bu)) * s;
}

extern "C" void kernel_launch(void* const* d_in, const int* in_sizes, int n_in,
                              void* d_out, int out_size, void* d_ws, size_t ws_size,
                              hipStream_t stream) {
    const float* X  = (const float*)d_in[0];
    const float* U  = (const float*)d_in[1];
    const float* x0 = (const float*)d_in[2];
    const float* A  = (const float*)d_in[3];
    const float* B  = (const float*)d_in[4];
    const float* C  = (const float*)d_in[5];
    float* out = (float*)d_out;
    _Float16* M = (_Float16*)d_ws;      // 640*320*2 = 409,600 B (fragment-ordered)

    build_M<<<800, 256, 0, stream>>>(A, C, M);
    gemm_main<<<4096, 256, 0, stream>>>(X, x0, M, out);
    xu_kernel<<<1875, 256, 0, stream>>>(X, U, B, out);
}